// Round 2
// baseline (93.502 us; speedup 1.0000x reference)
//
#include <hip/hip_runtime.h>
#include <hip/hip_cooperative_groups.h>

namespace cg = cooperative_groups;

// loss = -1.5 * sum_c |S_c|^2 + Q + 0.5 * |T|^2
//   S_c = sum of feat rows with label c, T = total row sum, Q = sum feat^2.
// Single cooperative kernel, 3 phases:
//   P1: per-(rowgroup, dim-half) class-sum tables in LDS -> ws (no atomics;
//       thread owns one dim so LDS RMW needs no atomics either)
//   P2: fold 128 rowgroup tables per (class, dim-half) -> ssq + T partials
//   P3: block 0 combines scalars.

constexpr int D     = 256;
constexpr int DH    = 128;                 // dims per half
constexpr int NC    = 100;                 // labels in [0,100)
constexpr int TABSZ = NC * DH;             // 12800 floats / partial table
constexpr int NRG   = 128;                 // row groups
constexpr int NBLK  = NRG * 2;             // 256 blocks (x2 dim-halves)
constexpr int ROWS  = 64;                  // 8192 / NRG
// ws layout (floats)
constexpr size_t QOFF   = (size_t)NBLK * TABSZ;  // per-block q sums   [NBLK]
constexpr size_t SSQOFF = QOFF + NBLK;           // per-block ssq      [NBLK]
constexpr size_t TOFF   = SSQOFF + NBLK;         // per-block T parts  [NBLK*DH]

__global__ __launch_bounds__(128) void contrast_fused(
    const float* __restrict__ feat, const int* __restrict__ label,
    float* __restrict__ ws, float* __restrict__ out) {
  cg::grid_group grid = cg::this_grid();
  __shared__ float tab[TABSZ];
  __shared__ int   llab[ROWS];
  __shared__ float red[DH];

  const int t  = threadIdx.x;          // dim within half
  const int bp = blockIdx.x;
  const int dh = bp & 1;
  const int rg = bp >> 1;

  // ---- phase 1 ----
  for (int i = t; i < TABSZ; i += DH) tab[i] = 0.f;
  const int row0 = rg * ROWS;
  if (t < ROWS) llab[t] = label[row0 + t];
  __syncthreads();

  float q = 0.f;
  const float* fp = feat + (size_t)row0 * D + dh * DH + t;
  #pragma unroll 4
  for (int r = 0; r < ROWS; ++r) {
    const int   c = llab[r];
    const float v = fp[(size_t)r * D];
    tab[c * DH + t] += v;              // exclusive dim ownership: no atomics
    q += v * v;
  }
  __syncthreads();
  float* wt = ws + (size_t)bp * TABSZ;
  for (int i = t; i < TABSZ; i += DH) wt[i] = tab[i];
  red[t] = q;
  __syncthreads();
  #pragma unroll
  for (int s = 64; s > 0; s >>= 1) {
    if (t < s) red[t] += red[t + s];
    __syncthreads();
  }
  if (t == 0) ws[QOFF + bp] = red[0];

  grid.sync();

  // ---- phase 2: block (cpair=rg, dh) folds classes 2*rg, 2*rg+1 ----
  float ssq = 0.f, Tp = 0.f;
  if (rg * 2 < NC) {
    #pragma unroll
    for (int k = 0; k < 2; ++k) {
      const int c = rg * 2 + k;
      const float* base = ws + (size_t)dh * TABSZ + (size_t)c * DH + t;
      float S = 0.f;
      for (int g = 0; g < NRG; ++g) S += base[(size_t)g * 2 * TABSZ];
      ssq += S * S;
      Tp  += S;
    }
    ws[TOFF + (size_t)bp * DH + t] = Tp;
  }
  __syncthreads();
  red[t] = ssq;
  __syncthreads();
  #pragma unroll
  for (int s = 64; s > 0; s >>= 1) {
    if (t < s) red[t] += red[t + s];
    __syncthreads();
  }
  if (t == 0) ws[SSQOFF + bp] = red[0];   // inactive blocks write 0

  grid.sync();

  // ---- phase 3 ----
  if (bp == 0) {
    float qq = ws[QOFF + t]   + ws[QOFF + DH + t];
    float sq = ws[SSQOFF + t] + ws[SSQOFF + DH + t];
    float tt = 0.f;
    #pragma unroll
    for (int d2 = 0; d2 < 2; ++d2) {
      float T = 0.f;
      for (int cp = 0; cp * 2 < NC; ++cp)
        T += ws[TOFF + (size_t)(cp * 2 + d2) * DH + t];
      tt += T * T;
    }
    red[t] = qq; __syncthreads();
    #pragma unroll
    for (int s = 64; s > 0; s >>= 1) { if (t < s) red[t] += red[t + s]; __syncthreads(); }
    const float Q = red[0]; __syncthreads();
    red[t] = sq; __syncthreads();
    #pragma unroll
    for (int s = 64; s > 0; s >>= 1) { if (t < s) red[t] += red[t + s]; __syncthreads(); }
    const float SSQ = red[0]; __syncthreads();
    red[t] = tt; __syncthreads();
    #pragma unroll
    for (int s = 64; s > 0; s >>= 1) { if (t < s) red[t] += red[t + s]; __syncthreads(); }
    if (t == 0) out[0] = -1.5f * SSQ + Q + 0.5f * red[0];
  }
}

extern "C" void kernel_launch(void* const* d_in, const int* in_sizes, int n_in,
                              void* d_out, int out_size, void* d_ws, size_t ws_size,
                              hipStream_t stream) {
  (void)in_sizes; (void)n_in; (void)out_size; (void)ws_size;
  const float* feat  = (const float*)d_in[0];
  const int*   label = (const int*)d_in[1];
  float*       ws    = (float*)d_ws;
  float*       out   = (float*)d_out;
  void* args[] = {(void*)&feat, (void*)&label, (void*)&ws, (void*)&out};
  hipLaunchCooperativeKernel((const void*)contrast_fused, dim3(NBLK), dim3(DH),
                             args, 0, stream);
}

// Round 3
// 25.451 us; speedup vs baseline: 3.6739x; 3.6739x over previous
//
#include <hip/hip_runtime.h>

// loss = -1.5 * SSQ + Q + 0.5 * TT
//   S_c = sum of feat rows with label c; SSQ = sum_c |S_c|^2
//   T   = sum of all rows;               TT  = |T|^2
//   Q   = sum feat^2
// K1: 256 blocks (128 rowgroups x 2 dim-halves), per-block class tables in
//     LDS with 2 row-parity streams (private per-thread slices -> no atomics,
//     no sync, chain length 32) -> partial tables in ws.
// K2: 200 blocks (100 classes x 2 dim-halves) fold 128 partial tables ->
//     final S table + per-class-half ssq scalars.
// K3: 1 block combines TT, SSQ, Q -> out.

constexpr int D    = 256;
constexpr int NC   = 100;
constexpr int NRG  = 128;            // row groups
constexpr int ROWS = 64;             // rows per group
constexpr int NB1  = NRG * 2;        // 256 accum blocks
constexpr int TAB  = NC * 128;       // 12800 floats per partial table
// ws layout (floats)
constexpr size_t QOFF   = (size_t)NB1 * TAB;   // q partials      [256]
constexpr size_t SSQOFF = QOFF + NB1;          // ssq partials    [200]
constexpr size_t SOFF   = SSQOFF + 256;        // final S table   [NC][D]

__global__ __launch_bounds__(256) void k_accum(
    const float* __restrict__ feat, const int* __restrict__ label,
    float* __restrict__ ws) {
  __shared__ float tab[2 * TAB];     // [parity][class][128]  = 102.4 KB
  __shared__ int   llab[ROWS];
  __shared__ float red[256];
  const int tid = threadIdx.x;
  const int p   = tid >> 7;          // row-parity stream
  const int t   = tid & 127;         // dim within half
  const int bp  = blockIdx.x;
  const int rg  = bp >> 1, dh = bp & 1;
  const int row0 = rg * ROWS;

  if (tid < ROWS) llab[tid] = label[row0 + tid];
  float* myt = &tab[p * TAB + t];    // private slice: only (p,t) touches it
  #pragma unroll
  for (int c = 0; c < NC; ++c) myt[c * 128] = 0.f;
  __syncthreads();                   // llab ready (own slice needs no sync)

  const float* fp = feat + (size_t)(row0 + p) * D + dh * 128 + t;
  float q = 0.f;
  #pragma unroll 8
  for (int r = 0; r < ROWS / 2; ++r) {
    const int   c = llab[2 * r + p]; // wave-uniform -> broadcast
    const float v = fp[(size_t)(2 * r) * D];
    myt[c * 128] += v;
    q += v * v;
  }
  __syncthreads();

  float* wt = ws + (size_t)bp * TAB; // flush: sum the two parity tables
  for (int c = p * (NC / 2); c < (p + 1) * (NC / 2); ++c)
    wt[c * 128 + t] = tab[c * 128 + t] + tab[TAB + c * 128 + t];

  red[tid] = q;
  __syncthreads();
  #pragma unroll
  for (int s = 128; s > 0; s >>= 1) {
    if (tid < s) red[tid] += red[tid + s];
    __syncthreads();
  }
  if (tid == 0) ws[QOFF + bp] = red[0];
}

__global__ __launch_bounds__(256) void k_fold(float* __restrict__ ws) {
  const int tid = threadIdx.x;
  const int gp  = tid >> 7;          // rowgroup-parity split
  const int t   = tid & 127;
  const int cb  = blockIdx.x;        // 200: class * 2 + dim-half
  const int c   = cb >> 1, dh = cb & 1;
  // table bp = 2g + dh; g = 2j + gp  ->  bp = 4j + 2gp + dh
  const float* base = ws + (size_t)(2 * gp + dh) * TAB + (size_t)c * 128 + t;
  float Sp = 0.f;
  #pragma unroll 16
  for (int j = 0; j < NRG / 2; ++j) Sp += base[(size_t)4 * j * TAB];
  __shared__ float sh[256];
  sh[tid] = Sp;
  __syncthreads();
  float S = 0.f;
  if (tid < 128) {
    S = sh[t] + sh[128 + t];
    ws[SOFF + (size_t)c * D + dh * 128 + t] = S;
  }
  __syncthreads();
  sh[tid] = S * S;                   // upper half contributes 0
  __syncthreads();
  #pragma unroll
  for (int s = 128; s > 0; s >>= 1) {
    if (tid < s) sh[tid] += sh[tid + s];
    __syncthreads();
  }
  if (tid == 0) ws[SSQOFF + cb] = sh[0];
}

__global__ __launch_bounds__(256) void k_finish(
    const float* __restrict__ ws, float* __restrict__ out) {
  const int t = threadIdx.x;         // 256 = dim
  const float* Sv = ws + SOFF;
  float T = 0.f;
  #pragma unroll 10
  for (int c = 0; c < NC; ++c) T += Sv[(size_t)c * D + t];
  const float ssq = (t < 2 * NC) ? ws[SSQOFF + t] : 0.f;
  const float q   = ws[QOFF + t];
  __shared__ float red[256];
  red[t] = T * T;
  __syncthreads();
  #pragma unroll
  for (int s = 128; s > 0; s >>= 1) { if (t < s) red[t] += red[t + s]; __syncthreads(); }
  const float TT = red[0];
  __syncthreads();
  red[t] = ssq;
  __syncthreads();
  #pragma unroll
  for (int s = 128; s > 0; s >>= 1) { if (t < s) red[t] += red[t + s]; __syncthreads(); }
  const float SSQ = red[0];
  __syncthreads();
  red[t] = q;
  __syncthreads();
  #pragma unroll
  for (int s = 128; s > 0; s >>= 1) { if (t < s) red[t] += red[t + s]; __syncthreads(); }
  if (t == 0) out[0] = -1.5f * SSQ + red[0] + 0.5f * TT;
}

extern "C" void kernel_launch(void* const* d_in, const int* in_sizes, int n_in,
                              void* d_out, int out_size, void* d_ws, size_t ws_size,
                              hipStream_t stream) {
  (void)in_sizes; (void)n_in; (void)out_size; (void)ws_size;
  const float* feat  = (const float*)d_in[0];
  const int*   label = (const int*)d_in[1];
  float*       ws    = (float*)d_ws;
  k_accum<<<NB1, 256, 0, stream>>>(feat, label, ws);
  k_fold<<<2 * NC, 256, 0, stream>>>(ws);
  k_finish<<<1, 256, 0, stream>>>(ws, (float*)d_out);
}